// Round 17
// baseline (162.004 us; speedup 1.0000x reference)
//
#include <hip/hip_runtime.h>
#include <math.h>

#define Gn 64
#define Nn 1000
#define En 8192
#define Cc 128
#define HIDn 256
#define EPSf 1e-5f

typedef __attribute__((ext_vector_type(8))) short bh8;
typedef __attribute__((ext_vector_type(4))) float fx4;

__device__ __forceinline__ unsigned short f2bf(float f) {
    unsigned u = __float_as_uint(f);
    u += 0x7fffu + ((u >> 16) & 1u);
    return (unsigned short)(u >> 16);
}
__device__ __forceinline__ float bflo(unsigned u) { return __uint_as_float(u << 16); }
__device__ __forceinline__ float bfhi(unsigned u) { return __uint_as_float(u & 0xffff0000u); }
// tanh(x) = 1 - 2/(e^{2x}+1); e^{2x} = 2^{x*2.8853900818}. 5 VALU vs ~25 for tanhf.
__device__ __forceinline__ float tanh_fast(float x) {
    float e = exp2f(x * 2.885390081777927f);
    return 1.f - 2.f * __builtin_amdgcn_rcpf(e + 1.f);
}

// ---- k_wt: block 0: W0 -> Wt0g bf16 [n][k]; block 1: W1 -> Wt1g ----
__global__ __launch_bounds__(256) void k_wt(const float* __restrict__ W0, const float* __restrict__ W1,
                                            unsigned short* __restrict__ Wt0g,
                                            unsigned short* __restrict__ Wt1g)
{
    __shared__ __align__(16) short Wls[128][136];
    int t = threadIdx.x;
    const float* Wsrc = (blockIdx.x == 0) ? W0 : W1;
    unsigned short* Wdst = (blockIdx.x == 0) ? Wt0g : Wt1g;
    for (int idx = t; idx < 16384; idx += 256) {
        int kI = idx >> 7, n = idx & 127;
        Wls[n][kI] = (short)f2bf(Wsrc[idx]);
    }
    __syncthreads();
    for (int idx = t; idx < 2048; idx += 256) {
        int n = idx >> 4, kc = idx & 15;
        *(bh8*)(Wdst + (size_t)idx * 8) = *(const bh8*)&Wls[n][kc * 8];
    }
}

// ---- k_front: blocks 0..63 prep(graph b, 512t) | 64..575 gemm0 (8/graph, 128 rows/blk) ----
__global__ __launch_bounds__(512) void k_front(const int* __restrict__ ei, const float* __restrict__ X,
                                               const unsigned short* __restrict__ Wt0g,
                                               int4* __restrict__ ninfo, int2* __restrict__ epair,
                                               float* __restrict__ pooled, float* __restrict__ repr,
                                               int* __restrict__ bars,
                                               unsigned short* __restrict__ Hout)
{
    __shared__ __align__(16) short Wt[128][136];   // gemm staging; prep aliases front 8KB
    __shared__ int wsum[8];
    int t = threadIdx.x;
    int b = blockIdx.x;

    if (b < 64) {
        // ---------------- prep (512 threads, 2 nodes/thread wave-scan CSR build) ----------
        int* curs = (int*)&Wt[0][0];                       // 4KB (1024 ints)
        float* dinv_s = (float*)((char*)&Wt[0][0] + 4096); // 4KB
        int g = b;                                          // XCD g%8
        const int* srcp = ei + (size_t)g * 2 * En;
        const int* dstp = srcp + En;
        int lane = t & 63, wv = t >> 6;

        curs[t * 2] = 0; curs[t * 2 + 1] = 0;
        __syncthreads();
        for (int e = t; e < En; e += 512) atomicAdd(&curs[dstp[e]], 1);
        __syncthreads();

        int base = t * 2;
        int d0 = curs[base], d1 = curs[base + 1];
        int s = d0 + d1;
        int v = s;
        #pragma unroll
        for (int off = 1; off <= 32; off <<= 1) {
            int u = __shfl_up(v, off);
            if (lane >= off) v += u;
        }
        if (lane == 63) wsum[wv] = v;
        __syncthreads();
        int woff = 0;
        #pragma unroll
        for (int w = 0; w < 8; ++w) if (w < wv) woff += wsum[w];
        int e0 = woff + v - s;
        int e1 = e0 + d0;
        float dv0 = rsqrtf((float)d0 + 1.f), dv1 = rsqrtf((float)d1 + 1.f);
        curs[base] = e0; curs[base + 1] = e1;
        dinv_s[base] = dv0; dinv_s[base + 1] = dv1;
        if (base < Nn)     ninfo[g * Nn + base]     = make_int4(e0, d0, __float_as_int(dv0 * dv0), 0);
        if (base + 1 < Nn) ninfo[g * Nn + base + 1] = make_int4(e1, d1, __float_as_int(dv1 * dv1), 0);
        __syncthreads();

        for (int e = t; e < En; e += 512) {
            int dd = dstp[e], ss = srcp[e];
            int p = atomicAdd(&curs[dd], 1);
            float w = dinv_s[ss] * dinv_s[dd];
            epair[(size_t)g * En + p] = make_int2(ss << 8, __float_as_int(w));  // byte offset
        }
        if (t < Cc) pooled[g * Cc + t] = 0.f;      // accumulated by k_combine<1>
        if (g == 0 && t < Cc) repr[t] = 0.f;       // accumulated by k_tail
        if (g == 0 && t < 4) bars[t] = 0;          // completion ctr for k_tail
        return;
    }

    // ---------------- gemm0: H[g] = bf16(X[g] @ W0), pre-transposed bf16 W0 ---------------
    int bb = b - 64;                                // 0..511
    int xcd = bb & 7, gg = (bb >> 3) & 7, rblk = bb >> 6;   // graph on XCD g%8; rblk 0..7
    int g = xcd + 8 * gg;
    for (int idx = t; idx < 2048; idx += 512) {
        int n = idx >> 4, kc = idx & 15;
        *(bh8*)&Wt[n][kc * 8] = *(const bh8*)(Wt0g + (size_t)idx * 8);
    }
    __syncthreads();

    int wave = t >> 6, l = t & 63;                  // 8 waves x 16 rows = 128 rows/block
    int lr = l & 15, lg = l >> 4;
    const float* Xf = X + (size_t)g * Nn * Cc;
    unsigned short* Hg = Hout + (size_t)g * Nn * Cc;

    int rbase = rblk * 128 + wave * 16;
    int r = rbase + lr;
    bool ok = r < Nn;
    bh8 af[4];
    #pragma unroll
    for (int ks = 0; ks < 4; ++ks) {
        if (ok) {
            const float* xp = Xf + (size_t)r * Cc + ks * 32 + lg * 8;
            fx4 a0 = *(const fx4*)xp;
            fx4 a1 = *(const fx4*)(xp + 4);
            bh8 av;
            av[0] = (short)f2bf(a0[0]); av[1] = (short)f2bf(a0[1]);
            av[2] = (short)f2bf(a0[2]); av[3] = (short)f2bf(a0[3]);
            av[4] = (short)f2bf(a1[0]); av[5] = (short)f2bf(a1[1]);
            av[6] = (short)f2bf(a1[2]); av[7] = (short)f2bf(a1[3]);
            af[ks] = av;
        } else af[ks] = bh8{0, 0, 0, 0, 0, 0, 0, 0};
    }
    fx4 acc[8];
    #pragma unroll
    for (int ct = 0; ct < 8; ++ct) acc[ct] = fx4{0.f, 0.f, 0.f, 0.f};
    #pragma unroll
    for (int ks = 0; ks < 4; ++ks) {
        #pragma unroll
        for (int ct = 0; ct < 8; ++ct) {
            bh8 bfr = *(const bh8*)(&Wt[ct * 16 + lr][ks * 32 + lg * 8]);
            acc[ct] = __builtin_amdgcn_mfma_f32_16x16x32_bf16(af[ks], bfr, acc[ct], 0, 0, 0);
        }
    }
    // C/D layout: col = ct*16 + (lane&15), row = rbase + (lane>>4)*4 + reg
    #pragma unroll
    for (int ct = 0; ct < 8; ++ct) {
        #pragma unroll
        for (int rg = 0; rg < 4; ++rg) {
            int row = rbase + lg * 4 + rg;
            if (row < Nn) Hg[(size_t)row * Cc + ct * 16 + lr] = f2bf(acc[ct][rg]);
        }
    }
}

// ---- k_cg1: fused combine<0> + gemm1. 1024 blocks x 512t; 64 node-rows per block. -------
// Gather: 8 waves x 8 nodes/wave (combine structure, 4-deep) -> tanh rows -> LDS bf16 tile.
// Then 8 waves MFMA the 64x128 tile against pre-transposed W1 -> H.
__global__ __launch_bounds__(512) void k_cg1(const unsigned* __restrict__ Hb, const int2* __restrict__ epair,
                                             const int4* __restrict__ ninfo, const float* __restrict__ bias,
                                             const unsigned short* __restrict__ Wtg,
                                             unsigned short* __restrict__ Hout)
{
    __shared__ __align__(16) short Wt[128][136];
    __shared__ __align__(16) short Tl[64][136];
    int b = blockIdx.x;
    int xcd = b & 7, gg = (b >> 3) & 7, rblk = b >> 6;   // graph on XCD g%8; rblk 0..15
    int g = xcd + 8 * gg;
    int t = threadIdx.x, wv = t >> 6, lane = t & 63;

    for (int idx = t; idx < 2048; idx += 512) {
        int n = idx >> 4, kc = idx & 15;
        *(bh8*)&Wt[n][kc * 8] = *(const bh8*)(Wtg + (size_t)idx * 8);
    }
    __syncthreads();

    // ---- gather phase: wave wv owns local rows wv*8 .. wv*8+7 ----
    {
        const char* Hgc = (const char*)(Hb + (size_t)g * Nn * 64);
        const int2* epg = epair + (size_t)g * En;
        const int4* nig = ninfo + (size_t)g * Nn;
        float2 bb = *(const float2*)(bias + lane * 2);
        int lb4 = lane * 4;
        int rbase = rblk * 64;
        for (int i = 0; i < 8; ++i) {
            int lrow = wv * 8 + i;
            int n = rbase + lrow;
            unsigned packed = 0;
            if (n < Nn) {
                int4 ni = nig[n];
                int st = ni.x, dc = ni.y;
                float sw = __int_as_float(ni.z);
                unsigned hv = *(const unsigned*)(Hgc + n * 256 + lb4);
                float a0x = bflo(hv) * sw + bb.x, a0y = bfhi(hv) * sw + bb.y;
                float a1x = 0.f, a1y = 0.f, a2x = 0.f, a2y = 0.f, a3x = 0.f, a3y = 0.f;
                int e = 0;
                for (; e + 4 <= dc; e += 4) {
                    int2 p0 = epg[st + e];
                    int2 p1 = epg[st + e + 1];
                    int2 p2 = epg[st + e + 2];
                    int2 p3 = epg[st + e + 3];
                    unsigned r0 = *(const unsigned*)(Hgc + p0.x + lb4);
                    unsigned r1 = *(const unsigned*)(Hgc + p1.x + lb4);
                    unsigned r2 = *(const unsigned*)(Hgc + p2.x + lb4);
                    unsigned r3 = *(const unsigned*)(Hgc + p3.x + lb4);
                    float w0 = __int_as_float(p0.y), w1 = __int_as_float(p1.y);
                    float w2 = __int_as_float(p2.y), w3 = __int_as_float(p3.y);
                    a0x = fmaf(bflo(r0), w0, a0x); a0y = fmaf(bfhi(r0), w0, a0y);
                    a1x = fmaf(bflo(r1), w1, a1x); a1y = fmaf(bfhi(r1), w1, a1y);
                    a2x = fmaf(bflo(r2), w2, a2x); a2y = fmaf(bfhi(r2), w2, a2y);
                    a3x = fmaf(bflo(r3), w3, a3x); a3y = fmaf(bfhi(r3), w3, a3y);
                }
                for (; e < dc; ++e) {
                    int2 p0 = epg[st + e];
                    unsigned r0 = *(const unsigned*)(Hgc + p0.x + lb4);
                    float w0 = __int_as_float(p0.y);
                    a0x = fmaf(bflo(r0), w0, a0x); a0y = fmaf(bfhi(r0), w0, a0y);
                }
                float ax = (a0x + a1x) + (a2x + a3x);
                float ay = (a0y + a1y) + (a2y + a3y);
                packed = ((unsigned)f2bf(tanh_fast(ay)) << 16) | (unsigned)f2bf(tanh_fast(ax));
            }
            *(unsigned*)&Tl[lrow][lane * 2] = packed;   // wave-private rows: no barrier yet
        }
    }
    __syncthreads();

    // ---- MFMA phase: wave = 16-row tile (wv&3) x 64-col half (wv>>2) ----
    {
        int lr = lane & 15, lg = lane >> 4;
        int tb = (wv & 3) * 16;
        int ctb = (wv >> 2) * 4;
        unsigned short* Hg = Hout + (size_t)g * Nn * Cc;
        int rbase = rblk * 64;

        bh8 af[4];
        #pragma unroll
        for (int ks = 0; ks < 4; ++ks) af[ks] = *(const bh8*)&Tl[tb + lr][ks * 32 + lg * 8];
        fx4 acc[4];
        #pragma unroll
        for (int c2 = 0; c2 < 4; ++c2) acc[c2] = fx4{0.f, 0.f, 0.f, 0.f};
        #pragma unroll
        for (int ks = 0; ks < 4; ++ks) {
            #pragma unroll
            for (int c2 = 0; c2 < 4; ++c2) {
                bh8 bfr = *(const bh8*)(&Wt[(ctb + c2) * 16 + lr][ks * 32 + lg * 8]);
                acc[c2] = __builtin_amdgcn_mfma_f32_16x16x32_bf16(af[ks], bfr, acc[c2], 0, 0, 0);
            }
        }
        // C/D: col = (ctb+c2)*16 + lr, row = rbase + tb + lg*4 + rg
        #pragma unroll
        for (int c2 = 0; c2 < 4; ++c2) {
            #pragma unroll
            for (int rg = 0; rg < 4; ++rg) {
                int row = rbase + tb + lg * 4 + rg;
                if (row < Nn) Hg[(size_t)row * Cc + (ctb + c2) * 16 + lr] = f2bf(acc[c2][rg]);
            }
        }
    }
}

// ------- combine<1>: tanh(...) pooled accumulate; 4-deep, byte-offset epair ---------------
__global__ __launch_bounds__(256) void k_combine1(const unsigned* __restrict__ Hb, const int2* __restrict__ epair,
                                                  const int4* __restrict__ ninfo, const float* __restrict__ bias,
                                                  float* __restrict__ pooled)
{
    int b = blockIdx.x;
    int xcd = b & 7, j = b >> 3;
    int g = xcd + 8 * (j & 7);
    int blk = j >> 3;              // 0..31
    int wave = threadIdx.x >> 6, lane = threadIdx.x & 63;
    const char* Hgc = (const char*)(Hb + (size_t)g * Nn * 64);
    const int2* epg = epair + (size_t)g * En;
    const int4* nig = ninfo + (size_t)g * Nn;
    float2 bb = *(const float2*)(bias + lane * 2);
    int lb4 = lane * 4;
    float px = 0.f, py = 0.f;
    for (int n = blk * 4 + wave; n < Nn; n += 128) {
        int4 ni = nig[n];
        int st = ni.x, dc = ni.y;
        float sw = __int_as_float(ni.z);
        unsigned hv = *(const unsigned*)(Hgc + n * 256 + lb4);
        float a0x = bflo(hv) * sw + bb.x, a0y = bfhi(hv) * sw + bb.y;
        float a1x = 0.f, a1y = 0.f, a2x = 0.f, a2y = 0.f, a3x = 0.f, a3y = 0.f;
        int e = 0;
        for (; e + 4 <= dc; e += 4) {
            int2 p0 = epg[st + e];
            int2 p1 = epg[st + e + 1];
            int2 p2 = epg[st + e + 2];
            int2 p3 = epg[st + e + 3];
            unsigned r0 = *(const unsigned*)(Hgc + p0.x + lb4);
            unsigned r1 = *(const unsigned*)(Hgc + p1.x + lb4);
            unsigned r2 = *(const unsigned*)(Hgc + p2.x + lb4);
            unsigned r3 = *(const unsigned*)(Hgc + p3.x + lb4);
            float w0 = __int_as_float(p0.y), w1 = __int_as_float(p1.y);
            float w2 = __int_as_float(p2.y), w3 = __int_as_float(p3.y);
            a0x = fmaf(bflo(r0), w0, a0x); a0y = fmaf(bfhi(r0), w0, a0y);
            a1x = fmaf(bflo(r1), w1, a1x); a1y = fmaf(bfhi(r1), w1, a1y);
            a2x = fmaf(bflo(r2), w2, a2x); a2y = fmaf(bfhi(r2), w2, a2y);
            a3x = fmaf(bflo(r3), w3, a3x); a3y = fmaf(bfhi(r3), w3, a3y);
        }
        for (; e < dc; ++e) {
            int2 p0 = epg[st + e];
            unsigned r0 = *(const unsigned*)(Hgc + p0.x + lb4);
            float w0 = __int_as_float(p0.y);
            a0x = fmaf(bflo(r0), w0, a0x); a0y = fmaf(bfhi(r0), w0, a0y);
        }
        float ax = (a0x + a1x) + (a2x + a3x);
        float ay = (a0y + a1y) + (a2y + a3y);
        px += tanh_fast(ax);
        py += tanh_fast(ay);
    }
    atomicAdd(&pooled[g * Cc + lane * 2], px);
    atomicAdd(&pooled[g * Cc + lane * 2 + 1], py);
}

// ---------------- qkv: one wave per output column (coalesced rows + shuffle reduce) -------
__global__ __launch_bounds__(1024) void k_qkv(const float* __restrict__ pooled, const float* __restrict__ in_w,
                                              const float* __restrict__ in_b, float* __restrict__ qkvb)
{
    int t = threadIdx.x, lane = t & 63, wv = t >> 6;
    int c = blockIdx.x * 16 + wv;          // 24 blocks * 16 waves = 384 columns
    const float* wr = in_w + c * Cc;
    float w0 = wr[lane], w1 = wr[64 + lane];
    float bias = in_b[c];
    for (int i = 0; i < Gn; ++i) {
        float p = fmaf(pooled[i * Cc + lane], w0, pooled[i * Cc + 64 + lane] * w1);
        #pragma unroll
        for (int off2 = 32; off2 > 0; off2 >>= 1) p += __shfl_xor(p, off2);
        if (lane == 0) qkvb[i * 384 + c] = p + bias;
    }
}

// ------ tail: per-graph attention row + out-proj + MLP + LN + relu-sum; last block logits --
__global__ __launch_bounds__(512) void k_tail(const float* __restrict__ qkvb, const float* __restrict__ out_w,
                                              const float* __restrict__ out_b, const float* __restrict__ mw1,
                                              const float* __restrict__ mb1, const float* __restrict__ mw2,
                                              const float* __restrict__ mb2, const float* __restrict__ ln2g,
                                              const float* __restrict__ ln2b, const float* __restrict__ lw,
                                              const float* __restrict__ lb, float* __restrict__ repr,
                                              int* __restrict__ ctr, float* __restrict__ out)
{
    __shared__ float kk[64][129];
    __shared__ float vv[64][129];
    __shared__ float qrow[128];
    __shared__ float S[4][64];
    __shared__ float sob[128];
    __shared__ float sxatt[128];
    __shared__ float sm1p[2][256];
    __shared__ float sm1[256];
    __shared__ float sp2[4][128];
    __shared__ float yb[128];
    __shared__ int slast;
    int g = blockIdx.x;                     // 64 blocks, 1 graph each
    int t = threadIdx.x, lane = t & 63, wv = t >> 6;

    for (int idx = t; idx < 8192; idx += 512) {
        int i = idx >> 7, c = idx & 127;
        kk[i][c] = qkvb[i * 384 + 128 + c];
        vv[i][c] = qkvb[i * 384 + 256 + c];
    }
    if (t < 128) qrow[t] = qkvb[g * 384 + t];
    __syncthreads();

    if (t < 256) {
        int h = t >> 6, jj = t & 63;
        int base = h * 32;
        float acc = 0.f;
        #pragma unroll
        for (int d = 0; d < 32; ++d) acc = fmaf(qrow[base + d], kk[jj][base + d], acc);
        S[h][jj] = acc * 0.17677669529663687f;
    }
    __syncthreads();
    if (wv < 4) {
        float val = S[wv][lane];
        float m = val;
        #pragma unroll
        for (int off = 32; off > 0; off >>= 1) m = fmaxf(m, __shfl_xor(m, off));
        float e2 = expf(val - m);
        float ssum = e2;
        #pragma unroll
        for (int off = 32; off > 0; off >>= 1) ssum += __shfl_xor(ssum, off);
        S[wv][lane] = e2 / ssum;
    }
    __syncthreads();
    if (t < 128) {
        int h = t >> 5, d = t & 31;
        int col = h * 32 + d;
        float acc = 0.f;
        #pragma unroll 4
        for (int j = 0; j < 64; ++j) acc = fmaf(S[h][j], vv[j][col], acc);
        sob[col] = acc;
    }
    __syncthreads();

    {
        float o0 = sob[lane], o1 = sob[64 + lane];
        for (int c = wv; c < Cc; c += 8) {
            const float* wr = out_w + c * Cc;
            float p = fmaf(o0, wr[lane], o1 * wr[64 + lane]);
            #pragma unroll
            for (int off = 32; off > 0; off >>= 1) p += __shfl_xor(p, off);
            if (lane == 0) sxatt[c] = p + out_b[c];
        }
    }
    __syncthreads();

    {
        int jc = t & 255, half = t >> 8;
        int k0b = half * 64;
        float a[8];
        #pragma unroll
        for (int u = 0; u < 8; ++u) a[u] = 0.f;
        for (int k0 = k0b; k0 < k0b + 64; k0 += 8) {
            #pragma unroll
            for (int u = 0; u < 8; ++u)
                a[u] = fmaf(sxatt[k0 + u], mw1[(size_t)(k0 + u) * HIDn + jc], a[u]);
        }
        sm1p[half][jc] = ((a[0] + a[1]) + (a[2] + a[3])) + ((a[4] + a[5]) + (a[6] + a[7]));
        __syncthreads();
        if (t < 256) sm1[t] = fmaxf(sm1p[0][t] + sm1p[1][t] + mb1[t], 0.f);
    }
    __syncthreads();

    {
        int c = t & 127, q = t >> 7;
        int j0b = q * 64;
        float a[8];
        #pragma unroll
        for (int u = 0; u < 8; ++u) a[u] = 0.f;
        for (int j0 = j0b; j0 < j0b + 64; j0 += 8) {
            #pragma unroll
            for (int u = 0; u < 8; ++u)
                a[u] = fmaf(sm1[j0 + u], mw2[(size_t)(j0 + u) * Cc + c], a[u]);
        }
        sp2[q][c] = ((a[0] + a[1]) + (a[2] + a[3])) + ((a[4] + a[5]) + (a[6] + a[7]));
        __syncthreads();
        if (t < 128) yb[t] = sxatt[t] + (sp2[0][t] + sp2[1][t]) + (sp2[2][t] + sp2[3][t]) + mb2[t];
    }
    __syncthreads();

    if (t < 64) {
        float v0 = yb[lane], v1 = yb[64 + lane];
        float s = v0 + v1;
        #pragma unroll
        for (int off = 32; off > 0; off >>= 1) s += __shfl_xor(s, off);
        float mu = s * (1.f / 128.f);
        float d0 = v0 - mu, d1 = v1 - mu;
        float vvr = d0 * d0 + d1 * d1;
        #pragma unroll
        for (int off = 32; off > 0; off >>= 1) vvr += __shfl_xor(vvr, off);
        float rstd = rsqrtf(vvr * (1.f / 128.f) + EPSf);
        float z0 = fmaxf(d0 * rstd * ln2g[lane] + ln2b[lane], 0.f);
        float z1 = fmaxf(d1 * rstd * ln2g[64 + lane] + ln2b[64 + lane], 0.f);
        atomicAdd(&repr[lane], z0);
        atomicAdd(&repr[64 + lane], z1);
    }

    __threadfence();
    __syncthreads();
    if (t == 0) slast = atomicAdd(ctr, 1);
    __syncthreads();
    if (slast == 63) {
        __threadfence();
        __shared__ float r0s[128], r1s[128];
        if (t < 128) {
            float r = __hip_atomic_load(&repr[t], __ATOMIC_RELAXED, __HIP_MEMORY_SCOPE_AGENT);
            r0s[t] = r * lw[t * 2 + 0];
            r1s[t] = r * lw[t * 2 + 1];
        }
        __syncthreads();
        for (int s2 = 64; s2 > 0; s2 >>= 1) {
            if (t < s2) { r0s[t] += r0s[t + s2]; r1s[t] += r1s[t + s2]; }
            __syncthreads();
        }
        if (t == 0) { out[0] = r0s[0] + lb[0]; out[1] = r1s[0] + lb[1]; }
    }
}

extern "C" void kernel_launch(void* const* d_in, const int* in_sizes, int n_in,
                              void* d_out, int out_size, void* d_ws, size_t ws_size,
                              hipStream_t stream)
{
    const float* x     = (const float*)d_in[0];
    const int*   ei    = (const int*)d_in[1];
    const float* W0    = (const float*)d_in[2];
    const float* b0    = (const float*)d_in[3];
    const float* W1    = (const float*)d_in[4];
    const float* b1    = (const float*)d_in[5];
    const float* in_w  = (const float*)d_in[6];
    const float* in_b  = (const float*)d_in[7];
    const float* out_w = (const float*)d_in[8];
    const float* out_b = (const float*)d_in[9];
    const float* ln2g  = (const float*)d_in[10];
    const float* ln2b  = (const float*)d_in[11];
    const float* mw1   = (const float*)d_in[12];
    const float* mb1   = (const float*)d_in[13];
    const float* mw2   = (const float*)d_in[14];
    const float* mb2   = (const float*)d_in[15];
    const float* lw    = (const float*)d_in[16];
    const float* lb    = (const float*)d_in[17];
    float* out = (float*)d_out;
    (void)in_sizes; (void)n_in; (void)out_size; (void)ws_size;

    char* ws = (char*)d_ws;
    size_t off = 0;
    auto carve = [&](size_t bytes) { size_t o = off; off += (bytes + 255) & ~(size_t)255; return o; };
    size_t o_ni    = carve((size_t)Gn * Nn * 16);
    size_t o_ep    = carve((size_t)Gn * En * 8);
    size_t o_pool  = carve((size_t)Gn * Cc * 4);
    size_t o_qkv   = carve((size_t)Gn * 384 * 4);
    size_t o_repr  = carve((size_t)Cc * 4);
    size_t o_bars  = carve(256);
    size_t o_W0t   = carve((size_t)Cc * Cc * 2);
    size_t o_W1t   = carve((size_t)Cc * Cc * 2);
    size_t o_H     = carve((size_t)Gn * Nn * Cc * 2);
    size_t o_H2    = carve((size_t)Gn * Nn * Cc * 2);

    int4*  ninfo  = (int4*)(ws + o_ni);
    int2*  epair  = (int2*)(ws + o_ep);
    float* pooled = (float*)(ws + o_pool);
    float* qkvb   = (float*)(ws + o_qkv);
    float* repr   = (float*)(ws + o_repr);
    int*   bars   = (int*)(ws + o_bars);
    unsigned short* Wt0g = (unsigned short*)(ws + o_W0t);
    unsigned short* Wt1g = (unsigned short*)(ws + o_W1t);
    unsigned short* H  = (unsigned short*)(ws + o_H);
    unsigned short* H2 = (unsigned short*)(ws + o_H2);

    k_wt<<<2, 256, 0, stream>>>(W0, W1, Wt0g, Wt1g);
    k_front<<<576, 512, 0, stream>>>(ei, x, Wt0g, ninfo, epair, pooled, repr, bars, H);
    k_cg1<<<1024, 512, 0, stream>>>((const unsigned*)H, epair, ninfo, b0, Wt1g, H2);
    k_combine1<<<2048, 256, 0, stream>>>((const unsigned*)H2, epair, ninfo, b1, pooled);
    k_qkv<<<24, 1024, 0, stream>>>(pooled, in_w, in_b, qkvb);
    k_tail<<<64, 512, 0, stream>>>(qkvb, out_w, out_b, mw1, mb1, mw2, mb2, ln2g, ln2b,
                                   lw, lb, repr, &bars[2], out);
}

// Round 18
// 151.715 us; speedup vs baseline: 1.0678x; 1.0678x over previous
//
#include <hip/hip_runtime.h>
#include <math.h>

#define Gn 64
#define Nn 1000
#define En 8192
#define Cc 128
#define HIDn 256
#define EPSf 1e-5f

typedef __attribute__((ext_vector_type(8))) short bh8;
typedef __attribute__((ext_vector_type(4))) float fx4;

__device__ __forceinline__ unsigned short f2bf(float f) {
    unsigned u = __float_as_uint(f);
    u += 0x7fffu + ((u >> 16) & 1u);
    return (unsigned short)(u >> 16);
}
__device__ __forceinline__ float bflo(unsigned u) { return __uint_as_float(u << 16); }
__device__ __forceinline__ float bfhi(unsigned u) { return __uint_as_float(u & 0xffff0000u); }
// tanh(x) = 1 - 2/(e^{2x}+1); e^{2x} = 2^{x*2.8853900818}. 5 VALU vs ~25 for tanhf.
__device__ __forceinline__ float tanh_fast(float x) {
    float e = exp2f(x * 2.885390081777927f);
    return 1.f - 2.f * __builtin_amdgcn_rcpf(e + 1.f);
}

// ---- k_wt: block 0: W0 -> Wt0g bf16 [n][k]; block 1: W1 -> Wt1g ----
__global__ __launch_bounds__(256) void k_wt(const float* __restrict__ W0, const float* __restrict__ W1,
                                            unsigned short* __restrict__ Wt0g,
                                            unsigned short* __restrict__ Wt1g)
{
    __shared__ __align__(16) short Wls[128][136];
    int t = threadIdx.x;
    const float* Wsrc = (blockIdx.x == 0) ? W0 : W1;
    unsigned short* Wdst = (blockIdx.x == 0) ? Wt0g : Wt1g;
    for (int idx = t; idx < 16384; idx += 256) {
        int kI = idx >> 7, n = idx & 127;
        Wls[n][kI] = (short)f2bf(Wsrc[idx]);
    }
    __syncthreads();
    for (int idx = t; idx < 2048; idx += 256) {
        int n = idx >> 4, kc = idx & 15;
        *(bh8*)(Wdst + (size_t)idx * 8) = *(const bh8*)&Wls[n][kc * 8];
    }
}

// ---- k_front: blocks 0..63 prep(graph b, 512t) | 64..575 gemm0 (8/graph, 128 rows/blk) ----
__global__ __launch_bounds__(512) void k_front(const int* __restrict__ ei, const float* __restrict__ X,
                                               const unsigned short* __restrict__ Wt0g,
                                               int4* __restrict__ ninfo, int2* __restrict__ epair,
                                               float* __restrict__ pooled, float* __restrict__ repr,
                                               int* __restrict__ bars,
                                               unsigned short* __restrict__ Hout)
{
    __shared__ __align__(16) short Wt[128][136];   // gemm staging; prep aliases front 8KB
    __shared__ int wsum[8];
    int t = threadIdx.x;
    int b = blockIdx.x;

    if (b < 64) {
        // ---------------- prep (512 threads, 2 nodes/thread wave-scan CSR build) ----------
        int* curs = (int*)&Wt[0][0];                       // 4KB (1024 ints)
        float* dinv_s = (float*)((char*)&Wt[0][0] + 4096); // 4KB
        int g = b;                                          // XCD g%8
        const int* srcp = ei + (size_t)g * 2 * En;
        const int* dstp = srcp + En;
        int lane = t & 63, wv = t >> 6;

        curs[t * 2] = 0; curs[t * 2 + 1] = 0;
        __syncthreads();
        for (int e = t; e < En; e += 512) atomicAdd(&curs[dstp[e]], 1);
        __syncthreads();

        int base = t * 2;
        int d0 = curs[base], d1 = curs[base + 1];
        int s = d0 + d1;
        int v = s;
        #pragma unroll
        for (int off = 1; off <= 32; off <<= 1) {
            int u = __shfl_up(v, off);
            if (lane >= off) v += u;
        }
        if (lane == 63) wsum[wv] = v;
        __syncthreads();
        int woff = 0;
        #pragma unroll
        for (int w = 0; w < 8; ++w) if (w < wv) woff += wsum[w];
        int e0 = woff + v - s;
        int e1 = e0 + d0;
        float dv0 = rsqrtf((float)d0 + 1.f), dv1 = rsqrtf((float)d1 + 1.f);
        curs[base] = e0; curs[base + 1] = e1;
        dinv_s[base] = dv0; dinv_s[base + 1] = dv1;
        if (base < Nn)     ninfo[g * Nn + base]     = make_int4(e0, d0, __float_as_int(dv0 * dv0), 0);
        if (base + 1 < Nn) ninfo[g * Nn + base + 1] = make_int4(e1, d1, __float_as_int(dv1 * dv1), 0);
        __syncthreads();

        for (int e = t; e < En; e += 512) {
            int dd = dstp[e], ss = srcp[e];
            int p = atomicAdd(&curs[dd], 1);
            float w = dinv_s[ss] * dinv_s[dd];
            epair[(size_t)g * En + p] = make_int2(ss << 8, __float_as_int(w));  // byte offset
        }
        if (t < Cc) pooled[g * Cc + t] = 0.f;      // accumulated by k_combine<1>
        if (g == 0 && t < Cc) repr[t] = 0.f;       // accumulated by k_tail
        if (g == 0 && t < 4) bars[t] = 0;          // completion ctr for k_tail
        return;
    }

    // ---------------- gemm0: H[g] = bf16(X[g] @ W0), pre-transposed bf16 W0 ---------------
    int bb = b - 64;                                // 0..511
    int xcd = bb & 7, gg = (bb >> 3) & 7, rblk = bb >> 6;   // graph on XCD g%8; rblk 0..7
    int g = xcd + 8 * gg;
    for (int idx = t; idx < 2048; idx += 512) {
        int n = idx >> 4, kc = idx & 15;
        *(bh8*)&Wt[n][kc * 8] = *(const bh8*)(Wt0g + (size_t)idx * 8);
    }
    __syncthreads();

    int wave = t >> 6, l = t & 63;                  // 8 waves x 16 rows = 128 rows/block
    int lr = l & 15, lg = l >> 4;
    const float* Xf = X + (size_t)g * Nn * Cc;
    unsigned short* Hg = Hout + (size_t)g * Nn * Cc;

    int rbase = rblk * 128 + wave * 16;
    int r = rbase + lr;
    bool ok = r < Nn;
    bh8 af[4];
    #pragma unroll
    for (int ks = 0; ks < 4; ++ks) {
        if (ok) {
            const float* xp = Xf + (size_t)r * Cc + ks * 32 + lg * 8;
            fx4 a0 = *(const fx4*)xp;
            fx4 a1 = *(const fx4*)(xp + 4);
            bh8 av;
            av[0] = (short)f2bf(a0[0]); av[1] = (short)f2bf(a0[1]);
            av[2] = (short)f2bf(a0[2]); av[3] = (short)f2bf(a0[3]);
            av[4] = (short)f2bf(a1[0]); av[5] = (short)f2bf(a1[1]);
            av[6] = (short)f2bf(a1[2]); av[7] = (short)f2bf(a1[3]);
            af[ks] = av;
        } else af[ks] = bh8{0, 0, 0, 0, 0, 0, 0, 0};
    }
    fx4 acc[8];
    #pragma unroll
    for (int ct = 0; ct < 8; ++ct) acc[ct] = fx4{0.f, 0.f, 0.f, 0.f};
    #pragma unroll
    for (int ks = 0; ks < 4; ++ks) {
        #pragma unroll
        for (int ct = 0; ct < 8; ++ct) {
            bh8 bfr = *(const bh8*)(&Wt[ct * 16 + lr][ks * 32 + lg * 8]);
            acc[ct] = __builtin_amdgcn_mfma_f32_16x16x32_bf16(af[ks], bfr, acc[ct], 0, 0, 0);
        }
    }
    // C/D layout: col = ct*16 + (lane&15), row = rbase + (lane>>4)*4 + reg
    #pragma unroll
    for (int ct = 0; ct < 8; ++ct) {
        #pragma unroll
        for (int rg = 0; rg < 4; ++rg) {
            int row = rbase + lg * 4 + rg;
            if (row < Nn) Hg[(size_t)row * Cc + ct * 16 + lr] = f2bf(acc[ct][rg]);
        }
    }
}

// ------ gemm1: H[g] = bf16(T[g] @ W1), 16 blocks/graph, pre-transposed bf16 W1 ----------
__global__ __launch_bounds__(256) void k_gemm1(const unsigned short* __restrict__ Xh,
                                               const unsigned short* __restrict__ Wtg,
                                               unsigned short* __restrict__ Hout)
{
    __shared__ __align__(16) short Wt[128][136];
    int b = blockIdx.x;
    int xcd = b & 7, gg = (b >> 3) & 7, rblk = b >> 6;
    int g = xcd + 8 * gg;
    int t = threadIdx.x;
    for (int idx = t; idx < 2048; idx += 256) {
        int n = idx >> 4, kc = idx & 15;
        bh8 v = *(const bh8*)(Wtg + (size_t)idx * 8);
        *(bh8*)&Wt[n][kc * 8] = v;
    }
    __syncthreads();

    int wave = t >> 6, l = t & 63;
    int lr = l & 15, lg = l >> 4;
    const short* Xg = (const short*)Xh + (size_t)g * Nn * Cc;
    unsigned short* Hg = Hout + (size_t)g * Nn * Cc;

    int rbase = rblk * 64 + wave * 16;
    int r = rbase + lr;
    bool ok = r < Nn;
    bh8 af[4];
    #pragma unroll
    for (int ks = 0; ks < 4; ++ks) {
        if (ok) af[ks] = *(const bh8*)(Xg + (size_t)r * Cc + ks * 32 + lg * 8);
        else    af[ks] = bh8{0, 0, 0, 0, 0, 0, 0, 0};
    }
    fx4 acc[8];
    #pragma unroll
    for (int ct = 0; ct < 8; ++ct) acc[ct] = fx4{0.f, 0.f, 0.f, 0.f};
    #pragma unroll
    for (int ks = 0; ks < 4; ++ks) {
        #pragma unroll
        for (int ct = 0; ct < 8; ++ct) {
            bh8 bfr = *(const bh8*)(&Wt[ct * 16 + lr][ks * 32 + lg * 8]);
            acc[ct] = __builtin_amdgcn_mfma_f32_16x16x32_bf16(af[ks], bfr, acc[ct], 0, 0, 0);
        }
    }
    #pragma unroll
    for (int ct = 0; ct < 8; ++ct) {
        #pragma unroll
        for (int rg = 0; rg < 4; ++rg) {
            int row = rbase + lg * 4 + rg;
            if (row < Nn) Hg[(size_t)row * Cc + ct * 16 + lr] = f2bf(acc[ct][rg]);
        }
    }
}

// ------- combine: tanh(b + selfw*H[n] + sum_e w_e*H[src_e]); 4-deep, byte-offset epair -----
template<int POOL>
__global__ __launch_bounds__(256) void k_combine(const unsigned* __restrict__ Hb, const int2* __restrict__ epair,
                                                 const int4* __restrict__ ninfo, const float* __restrict__ bias,
                                                 unsigned* __restrict__ Tout, float* __restrict__ pooled)
{
    int b = blockIdx.x;
    int xcd = b & 7, j = b >> 3;
    int g = xcd + 8 * (j & 7);     // same XCD as this graph's GEMM blocks
    int blk = j >> 3;              // 0..31
    int wave = threadIdx.x >> 6, lane = threadIdx.x & 63;
    const char* Hgc = (const char*)(Hb + (size_t)g * Nn * 64);   // rows of 256B
    const int2* epg = epair + (size_t)g * En;
    const int4* nig = ninfo + (size_t)g * Nn;
    float2 bb = *(const float2*)(bias + lane * 2);
    int lb4 = lane * 4;
    float px = 0.f, py = 0.f;
    for (int n = blk * 4 + wave; n < Nn; n += 128) {
        int4 ni = nig[n];
        int st = ni.x, dc = ni.y;
        float sw = __int_as_float(ni.z);
        unsigned hv = *(const unsigned*)(Hgc + n * 256 + lb4);
        float a0x = bflo(hv) * sw + bb.x, a0y = bfhi(hv) * sw + bb.y;
        float a1x = 0.f, a1y = 0.f, a2x = 0.f, a2y = 0.f, a3x = 0.f, a3y = 0.f;
        int e = 0;
        for (; e + 4 <= dc; e += 4) {
            int2 p0 = epg[st + e];
            int2 p1 = epg[st + e + 1];
            int2 p2 = epg[st + e + 2];
            int2 p3 = epg[st + e + 3];
            unsigned r0 = *(const unsigned*)(Hgc + p0.x + lb4);
            unsigned r1 = *(const unsigned*)(Hgc + p1.x + lb4);
            unsigned r2 = *(const unsigned*)(Hgc + p2.x + lb4);
            unsigned r3 = *(const unsigned*)(Hgc + p3.x + lb4);
            float w0 = __int_as_float(p0.y), w1 = __int_as_float(p1.y);
            float w2 = __int_as_float(p2.y), w3 = __int_as_float(p3.y);
            a0x = fmaf(bflo(r0), w0, a0x); a0y = fmaf(bfhi(r0), w0, a0y);
            a1x = fmaf(bflo(r1), w1, a1x); a1y = fmaf(bfhi(r1), w1, a1y);
            a2x = fmaf(bflo(r2), w2, a2x); a2y = fmaf(bfhi(r2), w2, a2y);
            a3x = fmaf(bflo(r3), w3, a3x); a3y = fmaf(bfhi(r3), w3, a3y);
        }
        for (; e < dc; ++e) {
            int2 p0 = epg[st + e];
            unsigned r0 = *(const unsigned*)(Hgc + p0.x + lb4);
            float w0 = __int_as_float(p0.y);
            a0x = fmaf(bflo(r0), w0, a0x); a0y = fmaf(bfhi(r0), w0, a0y);
        }
        float ax = (a0x + a1x) + (a2x + a3x);
        float ay = (a0y + a1y) + (a2y + a3y);
        float tx = tanh_fast(ax), ty = tanh_fast(ay);
        if (POOL) { px += tx; py += ty; }
        else Tout[(size_t)(g * Nn + n) * 64 + lane] = ((unsigned)f2bf(ty) << 16) | (unsigned)f2bf(tx);
    }
    if (POOL) {
        atomicAdd(&pooled[g * Cc + lane * 2], px);
        atomicAdd(&pooled[g * Cc + lane * 2 + 1], py);
    }
}

// ---------------- qkv: one wave per output column (coalesced rows + shuffle reduce) -------
__global__ __launch_bounds__(1024) void k_qkv(const float* __restrict__ pooled, const float* __restrict__ in_w,
                                              const float* __restrict__ in_b, float* __restrict__ qkvb)
{
    int t = threadIdx.x, lane = t & 63, wv = t >> 6;
    int c = blockIdx.x * 16 + wv;          // 24 blocks * 16 waves = 384 columns
    const float* wr = in_w + c * Cc;
    float w0 = wr[lane], w1 = wr[64 + lane];
    float bias = in_b[c];
    for (int i = 0; i < Gn; ++i) {
        float p = fmaf(pooled[i * Cc + lane], w0, pooled[i * Cc + 64 + lane] * w1);
        #pragma unroll
        for (int off2 = 32; off2 > 0; off2 >>= 1) p += __shfl_xor(p, off2);
        if (lane == 0) qkvb[i * 384 + c] = p + bias;
    }
}

// ------ tail: per-graph attention row + out-proj + MLP + LN + relu-sum; last block logits --
__global__ __launch_bounds__(512) void k_tail(const float* __restrict__ qkvb, const float* __restrict__ out_w,
                                              const float* __restrict__ out_b, const float* __restrict__ mw1,
                                              const float* __restrict__ mb1, const float* __restrict__ mw2,
                                              const float* __restrict__ mb2, const float* __restrict__ ln2g,
                                              const float* __restrict__ ln2b, const float* __restrict__ lw,
                                              const float* __restrict__ lb, float* __restrict__ repr,
                                              int* __restrict__ ctr, float* __restrict__ out)
{
    __shared__ float kk[64][129];
    __shared__ float vv[64][129];
    __shared__ float qrow[128];
    __shared__ float S[4][64];
    __shared__ float sob[128];
    __shared__ float sxatt[128];
    __shared__ float sm1p[2][256];
    __shared__ float sm1[256];
    __shared__ float sp2[4][128];
    __shared__ float yb[128];
    __shared__ int slast;
    int g = blockIdx.x;                     // 64 blocks, 1 graph each
    int t = threadIdx.x, lane = t & 63, wv = t >> 6;

    for (int idx = t; idx < 8192; idx += 512) {
        int i = idx >> 7, c = idx & 127;
        kk[i][c] = qkvb[i * 384 + 128 + c];
        vv[i][c] = qkvb[i * 384 + 256 + c];
    }
    if (t < 128) qrow[t] = qkvb[g * 384 + t];
    __syncthreads();

    if (t < 256) {
        int h = t >> 6, jj = t & 63;
        int base = h * 32;
        float acc = 0.f;
        #pragma unroll
        for (int d = 0; d < 32; ++d) acc = fmaf(qrow[base + d], kk[jj][base + d], acc);
        S[h][jj] = acc * 0.17677669529663687f;
    }
    __syncthreads();
    if (wv < 4) {
        float val = S[wv][lane];
        float m = val;
        #pragma unroll
        for (int off = 32; off > 0; off >>= 1) m = fmaxf(m, __shfl_xor(m, off));
        float e2 = expf(val - m);
        float ssum = e2;
        #pragma unroll
        for (int off = 32; off > 0; off >>= 1) ssum += __shfl_xor(ssum, off);
        S[wv][lane] = e2 / ssum;
    }
    __syncthreads();
    if (t < 128) {
        int h = t >> 5, d = t & 31;
        int col = h * 32 + d;
        float acc = 0.f;
        #pragma unroll 4
        for (int j = 0; j < 64; ++j) acc = fmaf(S[h][j], vv[j][col], acc);
        sob[col] = acc;
    }
    __syncthreads();

    {
        float o0 = sob[lane], o1 = sob[64 + lane];
        for (int c = wv; c < Cc; c += 8) {
            const float* wr = out_w + c * Cc;
            float p = fmaf(o0, wr[lane], o1 * wr[64 + lane]);
            #pragma unroll
            for (int off = 32; off > 0; off >>= 1) p += __shfl_xor(p, off);
            if (lane == 0) sxatt[c] = p + out_b[c];
        }
    }
    __syncthreads();

    {
        int jc = t & 255, half = t >> 8;
        int k0b = half * 64;
        float a[8];
        #pragma unroll
        for (int u = 0; u < 8; ++u) a[u] = 0.f;
        for (int k0 = k0b; k0 < k0b + 64; k0 += 8) {
            #pragma unroll
            for (int u = 0; u < 8; ++u)
                a[u] = fmaf(sxatt[k0 + u], mw1[(size_t)(k0 + u) * HIDn + jc], a[u]);
        }
        sm1p[half][jc] = ((a[0] + a[1]) + (a[2] + a[3])) + ((a[4] + a[5]) + (a[6] + a[7]));
        __syncthreads();
        if (t < 256) sm1[t] = fmaxf(sm1p[0][t] + sm1p[1][t] + mb1[t], 0.f);
    }
    __syncthreads();

    {
        int c = t & 127, q = t >> 7;
        int j0b = q * 64;
        float a[8];
        #pragma unroll
        for (int u = 0; u < 8; ++u) a[u] = 0.f;
        for (int j0 = j0b; j0 < j0b + 64; j0 += 8) {
            #pragma unroll
            for (int u = 0; u < 8; ++u)
                a[u] = fmaf(sm1[j0 + u], mw2[(size_t)(j0 + u) * Cc + c], a[u]);
        }
        sp2[q][c] = ((a[0] + a[1]) + (a[2] + a[3])) + ((a[4] + a[5]) + (a[6] + a[7]));
        __syncthreads();
        if (t < 128) yb[t] = sxatt[t] + (sp2[0][t] + sp2[1][t]) + (sp2[2][t] + sp2[3][t]) + mb2[t];
    }
    __syncthreads();

    if (t < 64) {
        float v0 = yb[lane], v1 = yb[64 + lane];
        float s = v0 + v1;
        #pragma unroll
        for (int off = 32; off > 0; off >>= 1) s += __shfl_xor(s, off);
        float mu = s * (1.f / 128.f);
        float d0 = v0 - mu, d1 = v1 - mu;
        float vvr = d0 * d0 + d1 * d1;
        #pragma unroll
        for (int off = 32; off > 0; off >>= 1) vvr += __shfl_xor(vvr, off);
        float rstd = rsqrtf(vvr * (1.f / 128.f) + EPSf);
        float z0 = fmaxf(d0 * rstd * ln2g[lane] + ln2b[lane], 0.f);
        float z1 = fmaxf(d1 * rstd * ln2g[64 + lane] + ln2b[64 + lane], 0.f);
        atomicAdd(&repr[lane], z0);
        atomicAdd(&repr[64 + lane], z1);
    }

    __threadfence();
    __syncthreads();
    if (t == 0) slast = atomicAdd(ctr, 1);
    __syncthreads();
    if (slast == 63) {
        __threadfence();
        __shared__ float r0s[128], r1s[128];
        if (t < 128) {
            float r = __hip_atomic_load(&repr[t], __ATOMIC_RELAXED, __HIP_MEMORY_SCOPE_AGENT);
            r0s[t] = r * lw[t * 2 + 0];
            r1s[t] = r * lw[t * 2 + 1];
        }
        __syncthreads();
        for (int s2 = 64; s2 > 0; s2 >>= 1) {
            if (t < s2) { r0s[t] += r0s[t + s2]; r1s[t] += r1s[t + s2]; }
            __syncthreads();
        }
        if (t == 0) { out[0] = r0s[0] + lb[0]; out[1] = r1s[0] + lb[1]; }
    }
}

extern "C" void kernel_launch(void* const* d_in, const int* in_sizes, int n_in,
                              void* d_out, int out_size, void* d_ws, size_t ws_size,
                              hipStream_t stream)
{
    const float* x     = (const float*)d_in[0];
    const int*   ei    = (const int*)d_in[1];
    const float* W0    = (const float*)d_in[2];
    const float* b0    = (const float*)d_in[3];
    const float* W1    = (const float*)d_in[4];
    const float* b1    = (const float*)d_in[5];
    const float* in_w  = (const float*)d_in[6];
    const float* in_b  = (const float*)d_in[7];
    const float* out_w = (const float*)d_in[8];
    const float* out_b = (const float*)d_in[9];
    const float* ln2g  = (const float*)d_in[10];
    const float* ln2b  = (const float*)d_in[11];
    const float* mw1   = (const float*)d_in[12];
    const float* mb1   = (const float*)d_in[13];
    const float* mw2   = (const float*)d_in[14];
    const float* mb2   = (const float*)d_in[15];
    const float* lw    = (const float*)d_in[16];
    const float* lb    = (const float*)d_in[17];
    float* out = (float*)d_out;
    (void)in_sizes; (void)n_in; (void)out_size; (void)ws_size;

    char* ws = (char*)d_ws;
    size_t off = 0;
    auto carve = [&](size_t bytes) { size_t o = off; off += (bytes + 255) & ~(size_t)255; return o; };
    size_t o_ni    = carve((size_t)Gn * Nn * 16);
    size_t o_ep    = carve((size_t)Gn * En * 8);
    size_t o_pool  = carve((size_t)Gn * Cc * 4);
    size_t o_qkv   = carve((size_t)Gn * 384 * 4);
    size_t o_repr  = carve((size_t)Cc * 4);
    size_t o_bars  = carve(256);
    size_t o_W0t   = carve((size_t)Cc * Cc * 2);
    size_t o_W1t   = carve((size_t)Cc * Cc * 2);
    size_t o_H     = carve((size_t)Gn * Nn * Cc * 2);
    size_t o_T     = carve((size_t)Gn * Nn * Cc * 2);

    int4*  ninfo  = (int4*)(ws + o_ni);
    int2*  epair  = (int2*)(ws + o_ep);
    float* pooled = (float*)(ws + o_pool);
    float* qkvb   = (float*)(ws + o_qkv);
    float* repr   = (float*)(ws + o_repr);
    int*   bars   = (int*)(ws + o_bars);
    unsigned short* Wt0g = (unsigned short*)(ws + o_W0t);
    unsigned short* Wt1g = (unsigned short*)(ws + o_W1t);
    unsigned short* H  = (unsigned short*)(ws + o_H);
    unsigned short* T  = (unsigned short*)(ws + o_T);

    k_wt<<<2, 256, 0, stream>>>(W0, W1, Wt0g, Wt1g);
    k_front<<<576, 512, 0, stream>>>(ei, x, Wt0g, ninfo, epair, pooled, repr, bars, H);
    k_combine<0><<<2048, 256, 0, stream>>>((const unsigned*)H, epair, ninfo, b0, (unsigned*)T, nullptr);
    k_gemm1<<<1024, 256, 0, stream>>>(T, Wt1g, H);
    k_combine<1><<<2048, 256, 0, stream>>>((const unsigned*)H, epair, ninfo, b1, nullptr, pooled);
    k_qkv<<<24, 1024, 0, stream>>>(pooled, in_w, in_b, qkvb);
    k_tail<<<64, 512, 0, stream>>>(qkvb, out_w, out_b, mw1, mb1, mw2, mb2, ln2g, ln2b,
                                   lw, lb, repr, &bars[2], out);
}

// Round 19
// 147.401 us; speedup vs baseline: 1.0991x; 1.0293x over previous
//
#include <hip/hip_runtime.h>
#include <math.h>

#define Gn 64
#define Nn 1000
#define En 8192
#define Cc 128
#define HIDn 256
#define EPSf 1e-5f

typedef __attribute__((ext_vector_type(8))) short bh8;
typedef __attribute__((ext_vector_type(4))) float fx4;

__device__ __forceinline__ unsigned short f2bf(float f) {
    unsigned u = __float_as_uint(f);
    u += 0x7fffu + ((u >> 16) & 1u);
    return (unsigned short)(u >> 16);
}
__device__ __forceinline__ float bflo(unsigned u) { return __uint_as_float(u << 16); }
__device__ __forceinline__ float bfhi(unsigned u) { return __uint_as_float(u & 0xffff0000u); }
// tanh(x) = 1 - 2/(e^{2x}+1); e^{2x} = 2^{x*2.8853900818}. 5 VALU vs ~25 for tanhf.
__device__ __forceinline__ float tanh_fast(float x) {
    float e = exp2f(x * 2.885390081777927f);
    return 1.f - 2.f * __builtin_amdgcn_rcpf(e + 1.f);
}

// ---- k_front: blocks 0..63 prep(graph b) | 64..575 gemm0 (8/graph, in-block W0 cvt)
//      | block 576: W1 -> Wt1g bf16 [n][k] (consumed by k_gemm1, next kernel) ----
__global__ __launch_bounds__(512) void k_front(const int* __restrict__ ei, const float* __restrict__ X,
                                               const float* __restrict__ W0, const float* __restrict__ W1,
                                               int4* __restrict__ ninfo, int2* __restrict__ epair,
                                               float* __restrict__ pooled, float* __restrict__ repr,
                                               int* __restrict__ bars,
                                               unsigned short* __restrict__ Wt1g,
                                               unsigned short* __restrict__ Hout)
{
    __shared__ __align__(16) short Wt[128][136];   // gemm/transpose staging; prep aliases front 8KB
    __shared__ int wsum[8];
    int t = threadIdx.x;
    int b = blockIdx.x;

    if (b < 64) {
        // ---------------- prep (512 threads, 2 nodes/thread wave-scan CSR build) ----------
        int* curs = (int*)&Wt[0][0];                       // 4KB (1024 ints)
        float* dinv_s = (float*)((char*)&Wt[0][0] + 4096); // 4KB
        int g = b;                                          // XCD g%8
        const int* srcp = ei + (size_t)g * 2 * En;
        const int* dstp = srcp + En;
        int lane = t & 63, wv = t >> 6;

        curs[t * 2] = 0; curs[t * 2 + 1] = 0;
        __syncthreads();
        for (int e = t; e < En; e += 512) atomicAdd(&curs[dstp[e]], 1);
        __syncthreads();

        int base = t * 2;
        int d0 = curs[base], d1 = curs[base + 1];
        int s = d0 + d1;
        int v = s;
        #pragma unroll
        for (int off = 1; off <= 32; off <<= 1) {
            int u = __shfl_up(v, off);
            if (lane >= off) v += u;
        }
        if (lane == 63) wsum[wv] = v;
        __syncthreads();
        int woff = 0;
        #pragma unroll
        for (int w = 0; w < 8; ++w) if (w < wv) woff += wsum[w];
        int e0 = woff + v - s;
        int e1 = e0 + d0;
        float dv0 = rsqrtf((float)d0 + 1.f), dv1 = rsqrtf((float)d1 + 1.f);
        curs[base] = e0; curs[base + 1] = e1;
        dinv_s[base] = dv0; dinv_s[base + 1] = dv1;
        if (base < Nn)     ninfo[g * Nn + base]     = make_int4(e0, d0, __float_as_int(dv0 * dv0), 0);
        if (base + 1 < Nn) ninfo[g * Nn + base + 1] = make_int4(e1, d1, __float_as_int(dv1 * dv1), 0);
        __syncthreads();

        for (int e = t; e < En; e += 512) {
            int dd = dstp[e], ss = srcp[e];
            int p = atomicAdd(&curs[dd], 1);
            float w = dinv_s[ss] * dinv_s[dd];
            epair[(size_t)g * En + p] = make_int2(ss << 8, __float_as_int(w));  // byte offset
        }
        if (t < Cc) pooled[g * Cc + t] = 0.f;      // accumulated by k_combine<1>
        if (g == 0 && t < Cc) repr[t] = 0.f;       // accumulated by k_tail
        if (g == 0 && t < 4) bars[t] = 0;          // completion ctr for k_tail
        return;
    }

    if (b == 576) {
        // ---- W1 fp32 [k][n] -> Wt1g bf16 [n][k] (no consumer until k_gemm1) ----
        for (int idx = t; idx < 16384; idx += 512) {
            int kI = idx >> 7, n = idx & 127;
            Wt[n][kI] = (short)f2bf(W1[idx]);
        }
        __syncthreads();
        for (int idx = t; idx < 2048; idx += 512) {
            int n = idx >> 4, kc = idx & 15;
            *(bh8*)(Wt1g + (size_t)idx * 8) = *(const bh8*)&Wt[n][kc * 8];
        }
        return;
    }

    // ---------------- gemm0: H[g] = bf16(X[g] @ W0), in-block W0 transpose ----------------
    int bb = b - 64;                                // 0..511
    int xcd = bb & 7, gg = (bb >> 3) & 7, rblk = bb >> 6;   // graph on XCD g%8; rblk 0..7
    int g = xcd + 8 * gg;
    for (int idx = t; idx < 16384; idx += 512) {
        int kI = idx >> 7, n = idx & 127;
        Wt[n][kI] = (short)f2bf(W0[idx]);
    }
    __syncthreads();

    int wave = t >> 6, l = t & 63;                  // 8 waves x 16 rows = 128 rows/block
    int lr = l & 15, lg = l >> 4;
    const float* Xf = X + (size_t)g * Nn * Cc;
    unsigned short* Hg = Hout + (size_t)g * Nn * Cc;

    int rbase = rblk * 128 + wave * 16;
    int r = rbase + lr;
    bool ok = r < Nn;
    bh8 af[4];
    #pragma unroll
    for (int ks = 0; ks < 4; ++ks) {
        if (ok) {
            const float* xp = Xf + (size_t)r * Cc + ks * 32 + lg * 8;
            fx4 a0 = *(const fx4*)xp;
            fx4 a1 = *(const fx4*)(xp + 4);
            bh8 av;
            av[0] = (short)f2bf(a0[0]); av[1] = (short)f2bf(a0[1]);
            av[2] = (short)f2bf(a0[2]); av[3] = (short)f2bf(a0[3]);
            av[4] = (short)f2bf(a1[0]); av[5] = (short)f2bf(a1[1]);
            av[6] = (short)f2bf(a1[2]); av[7] = (short)f2bf(a1[3]);
            af[ks] = av;
        } else af[ks] = bh8{0, 0, 0, 0, 0, 0, 0, 0};
    }
    fx4 acc[8];
    #pragma unroll
    for (int ct = 0; ct < 8; ++ct) acc[ct] = fx4{0.f, 0.f, 0.f, 0.f};
    #pragma unroll
    for (int ks = 0; ks < 4; ++ks) {
        #pragma unroll
        for (int ct = 0; ct < 8; ++ct) {
            bh8 bfr = *(const bh8*)(&Wt[ct * 16 + lr][ks * 32 + lg * 8]);
            acc[ct] = __builtin_amdgcn_mfma_f32_16x16x32_bf16(af[ks], bfr, acc[ct], 0, 0, 0);
        }
    }
    // C/D layout: col = ct*16 + (lane&15), row = rbase + (lane>>4)*4 + reg
    #pragma unroll
    for (int ct = 0; ct < 8; ++ct) {
        #pragma unroll
        for (int rg = 0; rg < 4; ++rg) {
            int row = rbase + lg * 4 + rg;
            if (row < Nn) Hg[(size_t)row * Cc + ct * 16 + lr] = f2bf(acc[ct][rg]);
        }
    }
}

// ------ gemm1: H[g] = bf16(T[g] @ W1), 16 blocks/graph, pre-transposed bf16 W1 ----------
__global__ __launch_bounds__(256) void k_gemm1(const unsigned short* __restrict__ Xh,
                                               const unsigned short* __restrict__ Wtg,
                                               unsigned short* __restrict__ Hout)
{
    __shared__ __align__(16) short Wt[128][136];
    int b = blockIdx.x;
    int xcd = b & 7, gg = (b >> 3) & 7, rblk = b >> 6;
    int g = xcd + 8 * gg;
    int t = threadIdx.x;
    for (int idx = t; idx < 2048; idx += 256) {
        int n = idx >> 4, kc = idx & 15;
        bh8 v = *(const bh8*)(Wtg + (size_t)idx * 8);
        *(bh8*)&Wt[n][kc * 8] = v;
    }
    __syncthreads();

    int wave = t >> 6, l = t & 63;
    int lr = l & 15, lg = l >> 4;
    const short* Xg = (const short*)Xh + (size_t)g * Nn * Cc;
    unsigned short* Hg = Hout + (size_t)g * Nn * Cc;

    int rbase = rblk * 64 + wave * 16;
    int r = rbase + lr;
    bool ok = r < Nn;
    bh8 af[4];
    #pragma unroll
    for (int ks = 0; ks < 4; ++ks) {
        if (ok) af[ks] = *(const bh8*)(Xg + (size_t)r * Cc + ks * 32 + lg * 8);
        else    af[ks] = bh8{0, 0, 0, 0, 0, 0, 0, 0};
    }
    fx4 acc[8];
    #pragma unroll
    for (int ct = 0; ct < 8; ++ct) acc[ct] = fx4{0.f, 0.f, 0.f, 0.f};
    #pragma unroll
    for (int ks = 0; ks < 4; ++ks) {
        #pragma unroll
        for (int ct = 0; ct < 8; ++ct) {
            bh8 bfr = *(const bh8*)(&Wt[ct * 16 + lr][ks * 32 + lg * 8]);
            acc[ct] = __builtin_amdgcn_mfma_f32_16x16x32_bf16(af[ks], bfr, acc[ct], 0, 0, 0);
        }
    }
    #pragma unroll
    for (int ct = 0; ct < 8; ++ct) {
        #pragma unroll
        for (int rg = 0; rg < 4; ++rg) {
            int row = rbase + lg * 4 + rg;
            if (row < Nn) Hg[(size_t)row * Cc + ct * 16 + lr] = f2bf(acc[ct][rg]);
        }
    }
}

// ------- combine: tanh(b + selfw*H[n] + sum_e w_e*H[src_e]); 4-deep, byte-offset epair -----
template<int POOL>
__global__ __launch_bounds__(256) void k_combine(const unsigned* __restrict__ Hb, const int2* __restrict__ epair,
                                                 const int4* __restrict__ ninfo, const float* __restrict__ bias,
                                                 unsigned* __restrict__ Tout, float* __restrict__ pooled)
{
    int b = blockIdx.x;
    int xcd = b & 7, j = b >> 3;
    int g = xcd + 8 * (j & 7);     // same XCD as this graph's GEMM blocks
    int blk = j >> 3;              // 0..31
    int wave = threadIdx.x >> 6, lane = threadIdx.x & 63;
    const char* Hgc = (const char*)(Hb + (size_t)g * Nn * 64);   // rows of 256B
    const int2* epg = epair + (size_t)g * En;
    const int4* nig = ninfo + (size_t)g * Nn;
    float2 bb = *(const float2*)(bias + lane * 2);
    int lb4 = lane * 4;
    float px = 0.f, py = 0.f;
    for (int n = blk * 4 + wave; n < Nn; n += 128) {
        int4 ni = nig[n];
        int st = ni.x, dc = ni.y;
        float sw = __int_as_float(ni.z);
        unsigned hv = *(const unsigned*)(Hgc + n * 256 + lb4);
        float a0x = bflo(hv) * sw + bb.x, a0y = bfhi(hv) * sw + bb.y;
        float a1x = 0.f, a1y = 0.f, a2x = 0.f, a2y = 0.f, a3x = 0.f, a3y = 0.f;
        int e = 0;
        for (; e + 4 <= dc; e += 4) {
            int2 p0 = epg[st + e];
            int2 p1 = epg[st + e + 1];
            int2 p2 = epg[st + e + 2];
            int2 p3 = epg[st + e + 3];
            unsigned r0 = *(const unsigned*)(Hgc + p0.x + lb4);
            unsigned r1 = *(const unsigned*)(Hgc + p1.x + lb4);
            unsigned r2 = *(const unsigned*)(Hgc + p2.x + lb4);
            unsigned r3 = *(const unsigned*)(Hgc + p3.x + lb4);
            float w0 = __int_as_float(p0.y), w1 = __int_as_float(p1.y);
            float w2 = __int_as_float(p2.y), w3 = __int_as_float(p3.y);
            a0x = fmaf(bflo(r0), w0, a0x); a0y = fmaf(bfhi(r0), w0, a0y);
            a1x = fmaf(bflo(r1), w1, a1x); a1y = fmaf(bfhi(r1), w1, a1y);
            a2x = fmaf(bflo(r2), w2, a2x); a2y = fmaf(bfhi(r2), w2, a2y);
            a3x = fmaf(bflo(r3), w3, a3x); a3y = fmaf(bfhi(r3), w3, a3y);
        }
        for (; e < dc; ++e) {
            int2 p0 = epg[st + e];
            unsigned r0 = *(const unsigned*)(Hgc + p0.x + lb4);
            float w0 = __int_as_float(p0.y);
            a0x = fmaf(bflo(r0), w0, a0x); a0y = fmaf(bfhi(r0), w0, a0y);
        }
        float ax = (a0x + a1x) + (a2x + a3x);
        float ay = (a0y + a1y) + (a2y + a3y);
        float tx = tanh_fast(ax), ty = tanh_fast(ay);
        if (POOL) { px += tx; py += ty; }
        else Tout[(size_t)(g * Nn + n) * 64 + lane] = ((unsigned)f2bf(ty) << 16) | (unsigned)f2bf(tx);
    }
    if (POOL) {
        atomicAdd(&pooled[g * Cc + lane * 2], px);
        atomicAdd(&pooled[g * Cc + lane * 2 + 1], py);
    }
}

// ---------------- qkv: one wave per output column (coalesced rows + shuffle reduce) -------
__global__ __launch_bounds__(1024) void k_qkv(const float* __restrict__ pooled, const float* __restrict__ in_w,
                                              const float* __restrict__ in_b, float* __restrict__ qkvb)
{
    int t = threadIdx.x, lane = t & 63, wv = t >> 6;
    int c = blockIdx.x * 16 + wv;          // 24 blocks * 16 waves = 384 columns
    const float* wr = in_w + c * Cc;
    float w0 = wr[lane], w1 = wr[64 + lane];
    float bias = in_b[c];
    for (int i = 0; i < Gn; ++i) {
        float p = fmaf(pooled[i * Cc + lane], w0, pooled[i * Cc + 64 + lane] * w1);
        #pragma unroll
        for (int off2 = 32; off2 > 0; off2 >>= 1) p += __shfl_xor(p, off2);
        if (lane == 0) qkvb[i * 384 + c] = p + bias;
    }
}

// ------ tail: per-graph attention row + out-proj + MLP + LN + relu-sum; last block logits --
__global__ __launch_bounds__(512) void k_tail(const float* __restrict__ qkvb, const float* __restrict__ out_w,
                                              const float* __restrict__ out_b, const float* __restrict__ mw1,
                                              const float* __restrict__ mb1, const float* __restrict__ mw2,
                                              const float* __restrict__ mb2, const float* __restrict__ ln2g,
                                              const float* __restrict__ ln2b, const float* __restrict__ lw,
                                              const float* __restrict__ lb, float* __restrict__ repr,
                                              int* __restrict__ ctr, float* __restrict__ out)
{
    __shared__ float kk[64][129];
    __shared__ float vv[64][129];
    __shared__ float qrow[128];
    __shared__ float S[4][64];
    __shared__ float sob[128];
    __shared__ float sxatt[128];
    __shared__ float sm1p[2][256];
    __shared__ float sm1[256];
    __shared__ float sp2[4][128];
    __shared__ float yb[128];
    __shared__ int slast;
    int g = blockIdx.x;                     // 64 blocks, 1 graph each
    int t = threadIdx.x, lane = t & 63, wv = t >> 6;

    for (int idx = t; idx < 8192; idx += 512) {
        int i = idx >> 7, c = idx & 127;
        kk[i][c] = qkvb[i * 384 + 128 + c];
        vv[i][c] = qkvb[i * 384 + 256 + c];
    }
    if (t < 128) qrow[t] = qkvb[g * 384 + t];
    __syncthreads();

    if (t < 256) {
        int h = t >> 6, jj = t & 63;
        int base = h * 32;
        float acc = 0.f;
        #pragma unroll
        for (int d = 0; d < 32; ++d) acc = fmaf(qrow[base + d], kk[jj][base + d], acc);
        S[h][jj] = acc * 0.17677669529663687f;
    }
    __syncthreads();
    if (wv < 4) {
        float val = S[wv][lane];
        float m = val;
        #pragma unroll
        for (int off = 32; off > 0; off >>= 1) m = fmaxf(m, __shfl_xor(m, off));
        float e2 = expf(val - m);
        float ssum = e2;
        #pragma unroll
        for (int off = 32; off > 0; off >>= 1) ssum += __shfl_xor(ssum, off);
        S[wv][lane] = e2 / ssum;
    }
    __syncthreads();
    if (t < 128) {
        int h = t >> 5, d = t & 31;
        int col = h * 32 + d;
        float acc = 0.f;
        #pragma unroll 4
        for (int j = 0; j < 64; ++j) acc = fmaf(S[h][j], vv[j][col], acc);
        sob[col] = acc;
    }
    __syncthreads();

    {
        float o0 = sob[lane], o1 = sob[64 + lane];
        for (int c = wv; c < Cc; c += 8) {
            const float* wr = out_w + c * Cc;
            float p = fmaf(o0, wr[lane], o1 * wr[64 + lane]);
            #pragma unroll
            for (int off = 32; off > 0; off >>= 1) p += __shfl_xor(p, off);
            if (lane == 0) sxatt[c] = p + out_b[c];
        }
    }
    __syncthreads();

    {
        int jc = t & 255, half = t >> 8;
        int k0b = half * 64;
        float a[8];
        #pragma unroll
        for (int u = 0; u < 8; ++u) a[u] = 0.f;
        for (int k0 = k0b; k0 < k0b + 64; k0 += 8) {
            #pragma unroll
            for (int u = 0; u < 8; ++u)
                a[u] = fmaf(sxatt[k0 + u], mw1[(size_t)(k0 + u) * HIDn + jc], a[u]);
        }
        sm1p[half][jc] = ((a[0] + a[1]) + (a[2] + a[3])) + ((a[4] + a[5]) + (a[6] + a[7]));
        __syncthreads();
        if (t < 256) sm1[t] = fmaxf(sm1p[0][t] + sm1p[1][t] + mb1[t], 0.f);
    }
    __syncthreads();

    {
        int c = t & 127, q = t >> 7;
        int j0b = q * 64;
        float a[8];
        #pragma unroll
        for (int u = 0; u < 8; ++u) a[u] = 0.f;
        for (int j0 = j0b; j0 < j0b + 64; j0 += 8) {
            #pragma unroll
            for (int u = 0; u < 8; ++u)
                a[u] = fmaf(sm1[j0 + u], mw2[(size_t)(j0 + u) * Cc + c], a[u]);
        }
        sp2[q][c] = ((a[0] + a[1]) + (a[2] + a[3])) + ((a[4] + a[5]) + (a[6] + a[7]));
        __syncthreads();
        if (t < 128) yb[t] = sxatt[t] + (sp2[0][t] + sp2[1][t]) + (sp2[2][t] + sp2[3][t]) + mb2[t];
    }
    __syncthreads();

    if (t < 64) {
        float v0 = yb[lane], v1 = yb[64 + lane];
        float s = v0 + v1;
        #pragma unroll
        for (int off = 32; off > 0; off >>= 1) s += __shfl_xor(s, off);
        float mu = s * (1.f / 128.f);
        float d0 = v0 - mu, d1 = v1 - mu;
        float vvr = d0 * d0 + d1 * d1;
        #pragma unroll
        for (int off = 32; off > 0; off >>= 1) vvr += __shfl_xor(vvr, off);
        float rstd = rsqrtf(vvr * (1.f / 128.f) + EPSf);
        float z0 = fmaxf(d0 * rstd * ln2g[lane] + ln2b[lane], 0.f);
        float z1 = fmaxf(d1 * rstd * ln2g[64 + lane] + ln2b[64 + lane], 0.f);
        atomicAdd(&repr[lane], z0);
        atomicAdd(&repr[64 + lane], z1);
    }

    __threadfence();
    __syncthreads();
    if (t == 0) slast = atomicAdd(ctr, 1);
    __syncthreads();
    if (slast == 63) {
        __threadfence();
        __shared__ float r0s[128], r1s[128];
        if (t < 128) {
            float r = __hip_atomic_load(&repr[t], __ATOMIC_RELAXED, __HIP_MEMORY_SCOPE_AGENT);
            r0s[t] = r * lw[t * 2 + 0];
            r1s[t] = r * lw[t * 2 + 1];
        }
        __syncthreads();
        for (int s2 = 64; s2 > 0; s2 >>= 1) {
            if (t < s2) { r0s[t] += r0s[t + s2]; r1s[t] += r1s[t + s2]; }
            __syncthreads();
        }
        if (t == 0) { out[0] = r0s[0] + lb[0]; out[1] = r1s[0] + lb[1]; }
    }
}

extern "C" void kernel_launch(void* const* d_in, const int* in_sizes, int n_in,
                              void* d_out, int out_size, void* d_ws, size_t ws_size,
                              hipStream_t stream)
{
    const float* x     = (const float*)d_in[0];
    const int*   ei    = (const int*)d_in[1];
    const float* W0    = (const float*)d_in[2];
    const float* b0    = (const float*)d_in[3];
    const float* W1    = (const float*)d_in[4];
    const float* b1    = (const float*)d_in[5];
    const float* in_w  = (const float*)d_in[6];
    const float* in_b  = (const float*)d_in[7];
    const float* out_w = (const float*)d_in[8];
    const float* out_b = (const float*)d_in[9];
    const float* ln2g  = (const float*)d_in[10];
    const float* ln2b  = (const float*)d_in[11];
    const float* mw1   = (const float*)d_in[12];
    const float* mb1   = (const float*)d_in[13];
    const float* mw2   = (const float*)d_in[14];
    const float* mb2   = (const float*)d_in[15];
    const float* lw    = (const float*)d_in[16];
    const float* lb    = (const float*)d_in[17];
    float* out = (float*)d_out;
    (void)in_sizes; (void)n_in; (void)out_size; (void)ws_size;

    char* ws = (char*)d_ws;
    size_t off = 0;
    auto carve = [&](size_t bytes) { size_t o = off; off += (bytes + 255) & ~(size_t)255; return o; };
    size_t o_ni    = carve((size_t)Gn * Nn * 16);
    size_t o_ep    = carve((size_t)Gn * En * 8);
    size_t o_pool  = carve((size_t)Gn * Cc * 4);
    size_t o_qkv   = carve((size_t)Gn * 384 * 4);
    size_t o_repr  = carve((size_t)Cc * 4);
    size_t o_bars  = carve(256);
    size_t o_W1t   = carve((size_t)Cc * Cc * 2);
    size_t o_H     = carve((size_t)Gn * Nn * Cc * 2);
    size_t o_T     = carve((size_t)Gn * Nn * Cc * 2);

    int4*  ninfo  = (int4*)(ws + o_ni);
    int2*  epair  = (int2*)(ws + o_ep);
    float* pooled = (float*)(ws + o_pool);
    float* qkvb   = (float*)(ws + o_qkv);
    float* repr   = (float*)(ws + o_repr);
    int*   bars   = (int*)(ws + o_bars);
    unsigned short* Wt1g = (unsigned short*)(ws + o_W1t);
    unsigned short* H  = (unsigned short*)(ws + o_H);
    unsigned short* T  = (unsigned short*)(ws + o_T);

    k_front<<<577, 512, 0, stream>>>(ei, x, W0, W1, ninfo, epair, pooled, repr, bars, Wt1g, H);
    k_combine<0><<<2048, 256, 0, stream>>>((const unsigned*)H, epair, ninfo, b0, (unsigned*)T, nullptr);
    k_gemm1<<<1024, 256, 0, stream>>>(T, Wt1g, H);
    k_combine<1><<<2048, 256, 0, stream>>>((const unsigned*)H, epair, ninfo, b1, nullptr, pooled);
    k_qkv<<<24, 1024, 0, stream>>>(pooled, in_w, in_b, qkvb);
    k_tail<<<64, 512, 0, stream>>>(qkvb, out_w, out_b, mw1, mb1, mw2, mb2, ln2g, ln2b,
                                   lw, lb, repr, &bars[2], out);
}